// Round 9
// baseline (746.948 us; speedup 1.0000x reference)
//
#include <hip/hip_runtime.h>
#include <math.h>

// Problem constants (fixed by setup_inputs: B=8, UPD=32, PPD=64)
#define H      256
#define NH     8
#define DH     32
#define FFDIM  1024
#define L1     128      // DEPTH*UNIT_LEN
#define B1     512      // B*PPD
#define L2     512      // UPD*UNIT_LEN
#define B2     8        // nb
#define N1     (L1*B1)  // 65536
#define N2     (L2*B2)  // 4096

typedef unsigned short u16;
typedef unsigned short ushort4_t __attribute__((ext_vector_type(4)));
typedef unsigned short ushort8_t __attribute__((ext_vector_type(8)));
typedef short          short8_t  __attribute__((ext_vector_type(8)));
typedef float          f32x4     __attribute__((ext_vector_type(4)));

__device__ __forceinline__ float bf2f(u16 u) {
    union { unsigned int i; float f; } v; v.i = ((unsigned int)u) << 16; return v.f;
}
__device__ __forceinline__ u16 f2bf(float f) {
    union { float f; unsigned int i; } v; v.f = f;
    unsigned int x = v.i;
    return (u16)((x + 0x7fffu + ((x >> 16) & 1u)) >> 16);   // RNE
}

// ---------------- f32 -> bf16 preconvert (weights, once per launch) -------
__global__ __launch_bounds__(256) void k_f2bf(
    const float* __restrict__ in, u16* __restrict__ out, int n)
{
    const int i = (blockIdx.x * 256 + threadIdx.x) * 4;
    if (i >= n) return;
    const float4 v = *(const float4*)(in + i);
    ushort4_t o;
    o.x = f2bf(v.x); o.y = f2bf(v.y); o.z = f2bf(v.z); o.w = f2bf(v.w);
    *(ushort4_t*)(out + i) = o;
}

// ---------------- gather + embedding + positional encoding ----------------
__global__ __launch_bounds__(256) void k_gather(
    const int* __restrict__ units, const int* __restrict__ paths,
    const float* __restrict__ emb, u16* __restrict__ x,
    int* __restrict__ tokout, int mode, int Bv)
{
    const int wave = threadIdx.x >> 6, lane = threadIdx.x & 63;
    const int t = blockIdx.x * 4 + wave;          // token row (l*Bv + b)
    const int l = t / Bv, b = t - l * Bv;
    int tokid;
    if (mode == 0) {
        const int d = l >> 4, u = l & 15;
        const int col = (b >> 6) * 32 + paths[d * 512 + b];
        tokid = units[u * 256 + col];
    } else {
        const int w = l >> 4, u = l & 15;
        tokid = units[u * 256 + b * 32 + w];
    }
    if (lane == 0) tokout[t] = tokid;
    const int c = lane * 4;
    const float4 e = *(const float4*)(emb + (size_t)tokid * H + c);
    const float i0 = (float)(c >> 1);
    const float a0 = (float)l * expf(-0.07195578415606394f * i0);
    const float a1 = (float)l * expf(-0.07195578415606394f * (i0 + 1.0f));
    ushort4_t o;
    o.x = f2bf(e.x + sinf(a0));
    o.y = f2bf(e.y + cosf(a0));
    o.z = f2bf(e.z + sinf(a1));
    o.w = f2bf(e.w + cosf(a1));
    *(ushort4_t*)(x + (size_t)t * H + c) = o;
}

// ---------------- MFMA GEMM (generic M): Y = X @ W^T + bias (opt ReLU) ----
// gload_lds width16, linear dest + inv-swizzled source + swizzled ds_read.
#define BUF_U16 8192      // one buffer: X[128][32] + W[128][32] = 16 KB
__global__ __launch_bounds__(256) void k_gemm_mfma(
    const u16* __restrict__ X, const u16* __restrict__ W,
    const float* __restrict__ bias, u16* __restrict__ Y,
    int N, int K, int M, int relu)
{
    __shared__ __align__(16) u16 smem[2 * BUF_U16];
    const int t = threadIdx.x;
    const int mtiles = M >> 7;
    const int nwg = gridDim.x;
    const int bid = blockIdx.x;
    const int wg = (bid & 7) * (nwg >> 3) + (bid >> 3);   // XCD-chunked
    const int bm = (wg / mtiles) * 128;
    const int bn = (wg % mtiles) * 128;
    const int wave = t >> 6, lane = t & 63;
    const int wr = (wave >> 1) * 64, wc = (wave & 1) * 64;
    const int lrow = lane & 15;
    const int lg   = lane >> 4;

    const u16* gx[2]; const u16* gw[2];
    int ldsxo[2], ldswo[2];
    #pragma unroll
    for (int i = 0; i < 2; ++i) {
        const int c = wave * 2 + i;
        const int r = c * 16 + (lane >> 2);
        const int s = (lane & 3) ^ ((r >> 1) & 3);
        gx[i] = X + (size_t)(bm + r) * K + s * 8;
        gw[i] = W + (size_t)(bn + r) * K + s * 8;
        ldsxo[i] = c * 512;
        ldswo[i] = 4096 + c * 512;
    }
    int aoff[4], boff[4];
    #pragma unroll
    for (int m = 0; m < 4; ++m) {
        const int R = wr + m * 16 + lrow;
        aoff[m] = R * 32 + ((lg ^ ((R >> 1) & 3)) * 8);
    }
    #pragma unroll
    for (int n = 0; n < 4; ++n) {
        const int R = wc + n * 16 + lrow;
        boff[n] = 4096 + R * 32 + ((lg ^ ((R >> 1) & 3)) * 8);
    }

    f32x4 acc[4][4] = {};
    const int nt = K >> 5;

    #pragma unroll
    for (int i = 0; i < 2; ++i) {
        __builtin_amdgcn_global_load_lds(gx[i], &smem[ldsxo[i]], 16, 0, 0);
        __builtin_amdgcn_global_load_lds(gw[i], &smem[ldswo[i]], 16, 0, 0);
        gx[i] += 32; gw[i] += 32;
    }
    __syncthreads();

    int cur = 0;
    for (int ts = 0; ts < nt; ++ts) {
        if (ts + 1 < nt) {
            const int nb = (cur ^ 1) * BUF_U16;
            #pragma unroll
            for (int i = 0; i < 2; ++i) {
                __builtin_amdgcn_global_load_lds(gx[i], &smem[nb + ldsxo[i]], 16, 0, 0);
                __builtin_amdgcn_global_load_lds(gw[i], &smem[nb + ldswo[i]], 16, 0, 0);
                gx[i] += 32; gw[i] += 32;
            }
        }
        const int cb = cur * BUF_U16;
        short8_t a[4], b[4];
        #pragma unroll
        for (int m = 0; m < 4; ++m) a[m] = *(const short8_t*)&smem[cb + aoff[m]];
        #pragma unroll
        for (int n = 0; n < 4; ++n) b[n] = *(const short8_t*)&smem[cb + boff[n]];
        #pragma unroll
        for (int m = 0; m < 4; ++m)
            #pragma unroll
            for (int n = 0; n < 4; ++n)
                acc[m][n] = __builtin_amdgcn_mfma_f32_16x16x32_bf16(
                    a[m], b[n], acc[m][n], 0, 0, 0);
        __syncthreads();
        cur ^= 1;
    }

    float bv[4];
    #pragma unroll
    for (int n = 0; n < 4; ++n) bv[n] = bias[bn + wc + n * 16 + lrow];
    const int r0 = (lane >> 4) * 4;

    #pragma unroll
    for (int h = 0; h < 2; ++h) {
        if ((wave & 1) == h) {
            #pragma unroll
            for (int n = 0; n < 4; ++n) {
                const int lc = n * 16 + lrow;
                #pragma unroll
                for (int m = 0; m < 4; ++m) {
                    const int lr = wr + m * 16 + r0;
                    #pragma unroll
                    for (int j = 0; j < 4; ++j) {
                        float v = acc[m][n][j] + bv[n];
                        if (relu) v = fmaxf(v, 0.f);
                        smem[(lr + j) * 72 + lc] = f2bf(v);
                    }
                }
            }
        }
        __syncthreads();
        #pragma unroll
        for (int it = 0; it < 4; ++it) {
            const int slot = it * 256 + t;
            const int row = slot >> 3;
            const int seg = (slot & 7) * 8;
            *(ushort8_t*)(Y + (size_t)(bm + row) * M + bn + h * 64 + seg) =
                *(const ushort8_t*)&smem[row * 72 + seg];
        }
        __syncthreads();
    }
}

// ---- fused GEMM (M=256) + bias + residual + LayerNorm, bf16 out ----------
// tile 128 rows x 256 cols (full row), 512 threads = 8 waves (2 x 4).
// Y = LN(res + X@W^T + bias) * gs + gb ; Y,res row-aligned per block.
#define BUF2_U16 12288    // 24 KB: X[128][32] (4096 u16) + W[256][32] (8192)
#define EPI_STR  264      // epilogue row stride in u16
__global__ __launch_bounds__(512) void k_gemm_ln(
    const u16* __restrict__ X, const u16* __restrict__ W,
    const float* __restrict__ bias, const u16* __restrict__ res,
    const float* __restrict__ gs, const float* __restrict__ gb,
    u16* __restrict__ Y, int N, int K)
{
    // LDS: max(K-loop 2*12288, epilogue 128*264 + 1024 f32) = 35840 u16
    __shared__ __align__(16) u16 smem[35840];
    const int t = threadIdx.x;
    const int nwg = gridDim.x;
    const int bid = blockIdx.x;
    const int wg = (bid & 7) * (nwg >> 3) + (bid >> 3);   // XCD-chunked
    const int bm = wg * 128;
    const int wave = t >> 6, lane = t & 63;
    const int wrow = (wave >> 2) * 64;        // 0 / 64
    const int wcol = (wave & 3) * 64;         // 0 / 64 / 128 / 192
    const int lrow = lane & 15;
    const int lg   = lane >> 4;
    const int r0   = lg * 4;

    // staging: 24 chunks of 16 rows; chunks 0-7 = X rows, 8-23 = W rows
    const u16* gsrc[3]; int ldso[3];
    #pragma unroll
    for (int i = 0; i < 3; ++i) {
        const int c = wave * 3 + i;
        const int rr = (lane >> 2);
        const int s = (lane & 3);
        if (c < 8) {
            const int r = c * 16 + rr;
            gsrc[i] = X + (size_t)(bm + r) * K + (s ^ ((r >> 1) & 3)) * 8;
        } else {
            const int r = (c - 8) * 16 + rr;
            gsrc[i] = W + (size_t)r * K + (s ^ ((r >> 1) & 3)) * 8;
        }
        ldso[i] = c * 512;
    }
    int aoff[4], boff[4];
    #pragma unroll
    for (int m = 0; m < 4; ++m) {
        const int R = wrow + m * 16 + lrow;
        aoff[m] = R * 32 + ((lg ^ ((R >> 1) & 3)) * 8);
    }
    #pragma unroll
    for (int n = 0; n < 4; ++n) {
        const int R = wcol + n * 16 + lrow;
        boff[n] = 4096 + R * 32 + ((lg ^ ((R >> 1) & 3)) * 8);
    }

    f32x4 acc[4][4] = {};
    const int nt = K >> 5;

    #pragma unroll
    for (int i = 0; i < 3; ++i) {
        __builtin_amdgcn_global_load_lds(gsrc[i], &smem[ldso[i]], 16, 0, 0);
        gsrc[i] += 32;
    }
    __syncthreads();

    int cur = 0;
    for (int ts = 0; ts < nt; ++ts) {
        if (ts + 1 < nt) {
            const int nb = (cur ^ 1) * BUF2_U16;
            #pragma unroll
            for (int i = 0; i < 3; ++i) {
                __builtin_amdgcn_global_load_lds(gsrc[i], &smem[nb + ldso[i]], 16, 0, 0);
                gsrc[i] += 32;
            }
        }
        const int cb = cur * BUF2_U16;
        short8_t a[4], b[4];
        #pragma unroll
        for (int m = 0; m < 4; ++m) a[m] = *(const short8_t*)&smem[cb + aoff[m]];
        #pragma unroll
        for (int n = 0; n < 4; ++n) b[n] = *(const short8_t*)&smem[cb + boff[n]];
        #pragma unroll
        for (int m = 0; m < 4; ++m)
            #pragma unroll
            for (int n = 0; n < 4; ++n)
                acc[m][n] = __builtin_amdgcn_mfma_f32_16x16x32_bf16(
                    a[m], b[n], acc[m][n], 0, 0, 0);
        __syncthreads();
        cur ^= 1;
    }

    // ---- epilogue: + bias + residual, then LayerNorm over each 256-row ----
    float bv[4];
    #pragma unroll
    for (int n = 0; n < 4; ++n) bv[n] = bias[wcol + n * 16 + lrow];

    // stage residual rows coalesced into smem[row][EPI_STR]
    #pragma unroll
    for (int it = 0; it < 8; ++it) {
        const int slot = it * 512 + t;       // 4096 slots = 128 rows x 32 segs
        const int row = slot >> 5;
        const int seg = (slot & 31) * 8;
        *(ushort8_t*)&smem[row * EPI_STR + seg] =
            *(const ushort8_t*)(res + (size_t)(bm + row) * 256 + seg);
    }
    __syncthreads();

    float* sums = (float*)&smem[128 * EPI_STR];    // [128][8] f32 (4 s + 4 sq)

    float psum[4][4], psq[4][4];
    #pragma unroll
    for (int m = 0; m < 4; ++m) {
        #pragma unroll
        for (int j = 0; j < 4; ++j) {
            const int row = wrow + m * 16 + r0 + j;
            float s = 0.f, q = 0.f;
            #pragma unroll
            for (int n = 0; n < 4; ++n) {
                const int col = wcol + n * 16 + lrow;
                float v = acc[m][n][j] + bv[n] + bf2f(smem[row * EPI_STR + col]);
                acc[m][n][j] = v;
                s += v; q += v * v;
            }
            #pragma unroll
            for (int off = 1; off < 16; off <<= 1) {
                s += __shfl_xor(s, off);
                q += __shfl_xor(q, off);
            }
            psum[m][j] = s; psq[m][j] = q;
        }
    }
    if (lrow == 0) {
        #pragma unroll
        for (int m = 0; m < 4; ++m)
            #pragma unroll
            for (int j = 0; j < 4; ++j) {
                const int row = wrow + m * 16 + r0 + j;
                sums[row * 8 + (wave & 3)] = psum[m][j];
                sums[row * 8 + 4 + (wave & 3)] = psq[m][j];
            }
    }
    __syncthreads();

    #pragma unroll
    for (int m = 0; m < 4; ++m) {
        #pragma unroll
        for (int j = 0; j < 4; ++j) {
            const int row = wrow + m * 16 + r0 + j;
            const float s = sums[row*8+0] + sums[row*8+1] + sums[row*8+2] + sums[row*8+3];
            const float q = sums[row*8+4] + sums[row*8+5] + sums[row*8+6] + sums[row*8+7];
            const float mean = s * (1.f / 256.f);
            const float var  = q * (1.f / 256.f) - mean * mean;
            const float is   = rsqrtf(var + 1e-5f);
            #pragma unroll
            for (int n = 0; n < 4; ++n) {
                const int col = wcol + n * 16 + lrow;
                const float y = (acc[m][n][j] - mean) * is * gs[col] + gb[col];
                smem[row * EPI_STR + col] = f2bf(y);
            }
        }
    }
    __syncthreads();
    #pragma unroll
    for (int it = 0; it < 8; ++it) {
        const int slot = it * 512 + t;
        const int row = slot >> 5;
        const int seg = (slot & 31) * 8;
        *(ushort8_t*)(Y + (size_t)(bm + row) * 256 + seg) =
            *(const ushort8_t*)&smem[row * EPI_STR + seg];
    }
}

// ---------------- MFMA flash attention (swapped-operand, online softmax) ---
__global__ __launch_bounds__(256) void k_attn_mfma(
    const u16* __restrict__ qkv, const int* __restrict__ tok,
    u16* __restrict__ out, int L, int Bv)
{
    __shared__ __align__(16) u16 Ks[128][40];
    __shared__ __align__(16) u16 Vt[32][136];
    __shared__ __align__(16) u16 Pl[128][136];
    __shared__ int msk[128];
    const int t = threadIdx.x;
    const int wave = t >> 6, lane = t & 63;
    const int lq = lane & 15, lg = lane >> 4;
    const int b = blockIdx.y >> 3, h = blockIdx.y & 7;
    const int q0 = blockIdx.x * 128 + wave * 32;
    const float scale = 0.17677669529663687f;

    short8_t qf[2];
    #pragma unroll
    for (int n = 0; n < 2; ++n)
        qf[n] = *(const short8_t*)(qkv +
            (size_t)((q0 + n * 16 + lq) * Bv + b) * 768 + h * DH + lg * 8);

    f32x4 o[2][2] = {};
    float mrun[2] = {-1e9f, -1e9f};
    float lrun[2] = {0.f, 0.f};

    for (int kt = 0; kt < L; kt += 128) {
        #pragma unroll
        for (int it = 0; it < 2; ++it) {
            const int slot = t + it * 256;
            const int row = slot >> 2;
            const int seg = (slot & 3) * 8;
            const u16* base = qkv + (size_t)((kt + row) * Bv + b) * 768 + 256 + h * DH + seg;
            *(ushort8_t*)&Ks[row][seg] = *(const ushort8_t*)base;
            const ushort8_t v8 = *(const ushort8_t*)(base + 256);
            #pragma unroll
            for (int e = 0; e < 8; ++e) Vt[seg + e][row] = v8[e];
        }
        if (t < 128) msk[t] = tok[(size_t)(kt + t) * Bv + b];
        __syncthreads();

        #pragma unroll
        for (int n = 0; n < 2; ++n) {
            f32x4 s[8];
            #pragma unroll
            for (int mp = 0; mp < 8; ++mp) {
                const short8_t kf = *(const short8_t*)&Ks[mp * 16 + lq][lg * 8];
                s[mp] = __builtin_amdgcn_mfma_f32_16x16x32_bf16(
                    kf, qf[n], (f32x4){0.f, 0.f, 0.f, 0.f}, 0, 0, 0);
            }
            float mx = -3.0e38f;
            #pragma unroll
            for (int mp = 0; mp < 8; ++mp) {
                #pragma unroll
                for (int j = 0; j < 4; ++j) {
                    float v = s[mp][j] * scale;
                    v = (msk[mp * 16 + lg * 4 + j] == 0) ? -1e9f : v;
                    s[mp][j] = v;
                    mx = fmaxf(mx, v);
                }
            }
            mx = fmaxf(mx, __shfl_xor(mx, 16));
            mx = fmaxf(mx, __shfl_xor(mx, 32));
            const float mnew = fmaxf(mrun[n], mx);
            const float fac = __expf(mrun[n] - mnew);
            mrun[n] = mnew;
            lrun[n] *= fac;
            #pragma unroll
            for (int dt = 0; dt < 2; ++dt)
                #pragma unroll
                for (int j = 0; j < 4; ++j) o[dt][n][j] *= fac;
            float lsum = 0.f;
            #pragma unroll
            for (int mp = 0; mp < 8; ++mp) {
                const float p0 = __expf(s[mp][0] - mnew);
                const float p1 = __expf(s[mp][1] - mnew);
                const float p2 = __expf(s[mp][2] - mnew);
                const float p3 = __expf(s[mp][3] - mnew);
                lsum += (p0 + p1) + (p2 + p3);
                uint2 pk;
                pk.x = (unsigned)f2bf(p0) | ((unsigned)f2bf(p1) << 16);
                pk.y = (unsigned)f2bf(p2) | ((unsigned)f2bf(p3) << 16);
                *(uint2*)&Pl[wave * 32 + n * 16 + lq][mp * 16 + lg * 4] = pk;
            }
            lsum += __shfl_xor(lsum, 16);
            lsum += __shfl_xor(lsum, 32);
            lrun[n] += lsum;
        }

        #pragma unroll
        for (int kk = 0; kk < 4; ++kk) {
            short8_t pf[2];
            #pragma unroll
            for (int n = 0; n < 2; ++n)
                pf[n] = *(const short8_t*)&Pl[wave * 32 + n * 16 + lq][kk * 32 + lg * 8];
            #pragma unroll
            for (int dt = 0; dt < 2; ++dt) {
                const short8_t vf = *(const short8_t*)&Vt[dt * 16 + lq][kk * 32 + lg * 8];
                #pragma unroll
                for (int n = 0; n < 2; ++n)
                    o[dt][n] = __builtin_amdgcn_mfma_f32_16x16x32_bf16(
                        vf, pf[n], o[dt][n], 0, 0, 0);
            }
        }
        __syncthreads();
    }

    #pragma unroll
    for (int n = 0; n < 2; ++n) {
        const float inv = 1.f / lrun[n];
        const int q = q0 + n * 16 + lq;
        u16* op = out + (size_t)(q * Bv + b) * H + h * DH;
        #pragma unroll
        for (int dt = 0; dt < 2; ++dt)
            #pragma unroll
            for (int j = 0; j < 4; ++j)
                op[dt * 16 + lg * 4 + j] = f2bf(o[dt][n][j] * inv);
    }
}

// ---------------- fused residual + LayerNorm (f32 out, to d_out) ----------
__global__ __launch_bounds__(256) void k_add_ln_f32(
    const u16* __restrict__ x, const u16* __restrict__ r,
    const float* __restrict__ gs, const float* __restrict__ gb,
    float* __restrict__ y)
{
    const int wave = threadIdx.x >> 6, lane = threadIdx.x & 63;
    const size_t row = (size_t)blockIdx.x * 4 + wave;
    const int c = lane * 4;
    const ushort4_t xv = *(const ushort4_t*)(x + row * H + c);
    const ushort4_t rv = *(const ushort4_t*)(r + row * H + c);
    float v[4] = { bf2f(xv.x) + bf2f(rv.x), bf2f(xv.y) + bf2f(rv.y),
                   bf2f(xv.z) + bf2f(rv.z), bf2f(xv.w) + bf2f(rv.w) };
    float sum = v[0] + v[1] + v[2] + v[3];
    float sq  = v[0]*v[0] + v[1]*v[1] + v[2]*v[2] + v[3]*v[3];
    #pragma unroll
    for (int off = 1; off < 64; off <<= 1) {
        sum += __shfl_xor(sum, off);
        sq  += __shfl_xor(sq, off);
    }
    const float mean = sum * (1.f / H);
    const float var  = sq * (1.f / H) - mean * mean;
    const float is   = rsqrtf(var + 1e-5f);
    const float4 sv = *(const float4*)(gs + c);
    const float4 bv = *(const float4*)(gb + c);
    float4 o;
    o.x = (v[0] - mean) * is * sv.x + bv.x;
    o.y = (v[1] - mean) * is * sv.y + bv.y;
    o.z = (v[2] - mean) * is * sv.z + bv.z;
    o.w = (v[3] - mean) * is * sv.w + bv.w;
    *(float4*)(y + row * H + c) = o;
}

// --------------------------------------------------------------------------
extern "C" void kernel_launch(void* const* d_in, const int* in_sizes, int n_in,
                              void* d_out, int out_size, void* d_ws, size_t ws_size,
                              hipStream_t stream)
{
    const int* units = (const int*)d_in[0];
    const int* paths = (const int*)d_in[1];
    const float* emb = (const float*)d_in[4];          // f32 inputs
    const float* const* ep = (const float* const*)(d_in + 5);
    const float* const* od = (const float* const*)(d_in + 17);
    float* out = (float*)d_out;                        // f32 output

    u16* bufX   = (u16*)d_ws;
    u16* bufBig = bufX + (size_t)N1 * H;
    u16* bufO   = bufBig + (size_t)N1 * FFDIM;
    int* tokb   = (int*)(bufO + (size_t)N1 * H);
    u16* wbuf   = (u16*)(tokb + N1);                   // bf16 weights, 6.3 MB

    const int wqkv = 2 * 768 * H, wout = 2 * H * H,
              wff1 = 2 * FFDIM * H, wff2 = 2 * H * FFDIM;
    const int encstride = wqkv + wout + wff1 + wff2;
    const float* const* encs[2] = { ep, od };
    for (int e = 0; e < 2; ++e) {
        u16* wb = wbuf + (size_t)e * encstride;
        const float* const* w = encs[e];
        k_f2bf<<<wqkv / 1024, 256, 0, stream>>>(w[0], wb, wqkv);
        k_f2bf<<<wout / 1024, 256, 0, stream>>>(w[2], wb + wqkv, wout);
        k_f2bf<<<wff1 / 1024, 256, 0, stream>>>(w[6], wb + wqkv + wout, wff1);
        k_f2bf<<<wff2 / 1024, 256, 0, stream>>>(w[8], wb + wqkv + wout + wff1, wff2);
    }

    auto run = [&](const float* const* w, const u16* wb, int L, int Bv, int mode, float* fin) {
        const int N = L * Bv;
        k_gather<<<N / 4, 256, 0, stream>>>(units, paths, emb, bufX, tokb, mode, Bv);
        for (int layer = 0; layer < 2; ++layer) {
            const u16* qkv_w = wb + (size_t)layer * 768 * H;
            const u16* out_w = wb + wqkv + (size_t)layer * H * H;
            const u16* ff1_w = wb + wqkv + wout + (size_t)layer * FFDIM * H;
            const u16* ff2_w = wb + wqkv + wout + wff1 + (size_t)layer * H * FFDIM;
            const float* qkv_b = w[1]  + (size_t)layer * 768;
            const float* out_b = w[3]  + (size_t)layer * H;
            const float* ln1s  = w[4]  + (size_t)layer * H;
            const float* ln1b  = w[5]  + (size_t)layer * H;
            const float* ff1b  = w[7]  + (size_t)layer * FFDIM;
            const float* ff2b  = w[9]  + (size_t)layer * H;
            const float* ln2s  = w[10] + (size_t)layer * H;
            const float* ln2b  = w[11] + (size_t)layer * H;

            // qkv projection (N x 768)
            k_gemm_mfma<<<(N/128)*(768/128), 256, 0, stream>>>(bufX, qkv_w, qkv_b, bufBig, N, H, 768, 0);
            // attention -> bufO
            k_attn_mfma<<<dim3(L/128, Bv*NH), 256, 0, stream>>>(bufBig, tokb, bufO, L, Bv);
            // out-proj + residual(bufX) + LN1 -> bufX  (fused)
            k_gemm_ln<<<N/128, 512, 0, stream>>>(bufO, out_w, out_b, bufX, ln1s, ln1b, bufX, N, H);
            // ff1 + relu (N x 1024)
            k_gemm_mfma<<<(N/128)*(FFDIM/128), 256, 0, stream>>>(bufX, ff1_w, ff1b, bufBig, N, H, FFDIM, 1);
            if (layer == 0) {
                // ff2 + residual(bufX) + LN2 -> bufX  (fused)
                k_gemm_ln<<<N/128, 512, 0, stream>>>(bufBig, ff2_w, ff2b, bufX, ln2s, ln2b, bufX, N, FFDIM);
            } else {
                // ff2 -> bufO, then final residual+LN to f32 d_out
                k_gemm_mfma<<<(N/128)*(H/128), 256, 0, stream>>>(bufBig, ff2_w, ff2b, bufO, N, FFDIM, H, 0);
                k_add_ln_f32<<<N/4, 256, 0, stream>>>(bufX, bufO, ln2s, ln2b, fin);
            }
        }
    };

    run(ep, wbuf, L1, B1, 0, out);                                   // expaths
    run(od, wbuf + (size_t)encstride, L2, B2, 1, out + (size_t)N1 * H); // order_enc
}